// Round 8
// baseline (875.371 us; speedup 1.0000x reference)
//
#include <hip/hip_runtime.h>
#include <hip/hip_bf16.h>
#include <cstdint>

#define GAMMA 0.1f
#define NBINS 12500     // N/4 rows per bin
#define NSUB 8          // sub-streams per bin (append density)
#define CAPS 32         // records per (bin,sub); Poisson(18) mean -> ~100 global overflows
#define OVF_CAP 16384

typedef unsigned int  uint32;
typedef unsigned short ushort16;
typedef float f32x4 __attribute__((ext_vector_type(4)));
typedef __bf16 bf16x8 __attribute__((ext_vector_type(8)));

union U16x8 { uint4 u4; bf16x8 bv; };

static __device__ __forceinline__ ushort16 f2bf(float f) {
    union { float f; uint32 u; } x; x.f = f;
    uint32 r = (x.u + 0x7FFFu + ((x.u >> 16) & 1u)) >> 16;
    return (ushort16)r;
}
static __device__ __forceinline__ uint32 pack2bf(float lo, float hi) {
    return (uint32)f2bf(lo) | ((uint32)f2bf(hi) << 16);
}
static __device__ __forceinline__ float bflo(uint32 u) { return __uint_as_float(u << 16); }
static __device__ __forceinline__ float bfhi(uint32 u) { return __uint_as_float(u & 0xFFFF0000u); }

// ---------- prep: W1^T, W2^T bf16 + zero bin counters ----------
__global__ __launch_bounds__(256) void prep_wt(const float* __restrict__ W1,
                                               const float* __restrict__ W2,
                                               ushort16* __restrict__ W1bt,
                                               ushort16* __restrict__ W2bt,
                                               int* __restrict__ bcnt) {
    int t = blockIdx.x * 256 + threadIdx.x;
    if (t < 128 * 512) { int c = t >> 9, k = t & 511; W1bt[t] = f2bf(W1[k * 128 + c]); }
    if (t < 48 * 128)  { int c = t >> 7, k = t & 127; W2bt[t] = f2bf(c < 40 ? W2[k * 40 + c] : 0.f); }
    for (int j = t; j < NBINS * NSUB + 1; j += 256 * 256) bcnt[j] = 0;
}

// ---------- fused: GEMM1 (blocks [0,mgrid)) + bin-scatter (rest) ----------
// record: x = col | (row&3)<<16 | type<<18 ; y = bf16(val) bits
__global__ __launch_bounds__(256) void gemm1_scatter(
    const float* __restrict__ A, const ushort16* __restrict__ Bt,
    const float* __restrict__ s1w, const float* __restrict__ d1w,
    const float* __restrict__ s1b, const float* __restrict__ d1b,
    ushort16* __restrict__ Cb, float* __restrict__ s_out, float* __restrict__ dk_out,
    int M, int mgrid,
    const int* __restrict__ arow_, const int* __restrict__ acol_, const float* __restrict__ aval_, int E,
    const int* __restrict__ krow_, const int* __restrict__ kcol_, const float* __restrict__ kval_, int EK,
    int* __restrict__ bcnt, uint2* __restrict__ bins, uint2* __restrict__ ovf) {
    int bid = blockIdx.x;
    if (bid >= mgrid) {
        // ---------------- scatter path ----------------
        int i = (bid - mgrid) * 256 + threadIdx.x;
        int sub = bid & (NSUB - 1);
        int* ovf_cnt = bcnt + NBINS * NSUB;
        if (i < E) {
            int r = arow_[i];
            int col = acol_[i];
            uint32 vb = (uint32)f2bf(aval_[i]);
            int slot = (r >> 2) * NSUB + sub;
            int p = atomicAdd(&bcnt[slot], 1);
            uint32 rx = (uint32)col | ((uint32)(r & 3) << 16);
            if (p < CAPS) bins[(size_t)slot * CAPS + p] = make_uint2(rx, vb);
            else {
                int q = atomicAdd(ovf_cnt, 1);
                if (q < OVF_CAP) ovf[q] = make_uint2((uint32)r, (uint32)col | (vb << 16));
            }
        }
        if (i < EK) {
            int r = krow_[i];
            int col = kcol_[i];
            uint32 vb = (uint32)f2bf(kval_[i]);
            int slot = (r >> 2) * NSUB + sub;
            int p = atomicAdd(&bcnt[slot], 1);
            uint32 rx = (uint32)col | ((uint32)(r & 3) << 16) | (1u << 18);
            if (p < CAPS) bins[(size_t)slot * CAPS + p] = make_uint2(rx, vb);
            else {
                int q = atomicAdd(ovf_cnt, 1);
                if (q < OVF_CAP) ovf[q] = make_uint2((uint32)r | 0x10000u, (uint32)col | (vb << 16));
            }
        }
        return;
    }
    // ---------------- GEMM1 path ----------------
    int w = threadIdx.x >> 6, lane = threadIdx.x & 63;
    int row16 = lane & 15, kc = lane >> 4;
    int wrow0 = bid * 64 + w * 16;
    int r = wrow0 + row16;
    int rc = min(r, M - 1);
    const float* arow = A + (size_t)rc * 512;

    f32x4 acc[8];
    #pragma unroll
    for (int c = 0; c < 8; ++c) acc[c] = (f32x4){0.f, 0.f, 0.f, 0.f};
    float sdot = 0.f, ddot = 0.f;

    for (int ks = 0; ks < 16; ++ks) {
        int kb = ks * 32 + kc * 8;
        float4 a0 = *reinterpret_cast<const float4*>(arow + kb);
        float4 a1 = *reinterpret_cast<const float4*>(arow + kb + 4);
        float4 sw0 = *reinterpret_cast<const float4*>(s1w + kb);
        float4 sw1 = *reinterpret_cast<const float4*>(s1w + kb + 4);
        float4 dw0 = *reinterpret_cast<const float4*>(d1w + kb);
        float4 dw1 = *reinterpret_cast<const float4*>(d1w + kb + 4);
        sdot += a0.x * sw0.x + a0.y * sw0.y + a0.z * sw0.z + a0.w * sw0.w +
                a1.x * sw1.x + a1.y * sw1.y + a1.z * sw1.z + a1.w * sw1.w;
        ddot += a0.x * dw0.x + a0.y * dw0.y + a0.z * dw0.z + a0.w * dw0.w +
                a1.x * dw1.x + a1.y * dw1.y + a1.z * dw1.z + a1.w * dw1.w;
        U16x8 ua;
        ua.u4 = make_uint4(pack2bf(a0.x, a0.y), pack2bf(a0.z, a0.w),
                           pack2bf(a1.x, a1.y), pack2bf(a1.z, a1.w));
        #pragma unroll
        for (int c = 0; c < 8; ++c) {
            U16x8 ub;
            ub.u4 = *reinterpret_cast<const uint4*>(Bt + (size_t)(c * 16 + row16) * 512 + kb);
            acc[c] = __builtin_amdgcn_mfma_f32_16x16x32_bf16(ua.bv, ub.bv, acc[c], 0, 0, 0);
        }
    }

    sdot += __shfl_xor(sdot, 16); sdot += __shfl_xor(sdot, 32);
    ddot += __shfl_xor(ddot, 16); ddot += __shfl_xor(ddot, 32);
    if (kc == 0 && r < M) {
        s_out[r] = 1.f / (1.f + __expf(-(sdot + s1b[0])));
        dk_out[r] = ddot + d1b[0];
    }

    #pragma unroll
    for (int c = 0; c < 8; ++c) {
        #pragma unroll
        for (int i = 0; i < 4; ++i) {
            int orow = wrow0 + (lane >> 4) * 4 + i;
            if (orow < M) Cb[(size_t)orow * 128 + c * 16 + row16] = f2bf(acc[c][i]);
        }
    }
}

// ---------- GEMM2: sup2[M,40](f32)+sup2b(bf16) = embb[M,128](bf16) @ W2 ----------
__global__ __launch_bounds__(256) void gemm2_mfma(const ushort16* __restrict__ Ab,
                                                  const ushort16* __restrict__ Bt,
                                                  float* __restrict__ C,
                                                  ushort16* __restrict__ Cb,
                                                  int M) {
    int w = threadIdx.x >> 6, lane = threadIdx.x & 63;
    int row16 = lane & 15, kc = lane >> 4;
    int wrow0 = blockIdx.x * 64 + w * 16;
    int r = wrow0 + row16;
    int rc = min(r, M - 1);

    f32x4 acc[3];
    #pragma unroll
    for (int c = 0; c < 3; ++c) acc[c] = (f32x4){0.f, 0.f, 0.f, 0.f};

    #pragma unroll
    for (int ks = 0; ks < 4; ++ks) {
        int kb = ks * 32 + kc * 8;
        U16x8 ua;
        ua.u4 = *reinterpret_cast<const uint4*>(Ab + (size_t)rc * 128 + kb);
        #pragma unroll
        for (int c = 0; c < 3; ++c) {
            U16x8 ub;
            ub.u4 = *reinterpret_cast<const uint4*>(Bt + (size_t)(c * 16 + row16) * 128 + kb);
            acc[c] = __builtin_amdgcn_mfma_f32_16x16x32_bf16(ua.bv, ub.bv, acc[c], 0, 0, 0);
        }
    }

    #pragma unroll
    for (int c = 0; c < 3; ++c) {
        int col = c * 16 + row16;
        #pragma unroll
        for (int i = 0; i < 4; ++i) {
            int orow = wrow0 + (lane >> 4) * 4 + i;
            if (orow < M && col < 40) {
                C[(size_t)orow * 40 + col] = acc[c][i];
                Cb[(size_t)orow * 40 + col] = f2bf(acc[c][i]);
            }
        }
    }
}

// ---------- layer-1 SPMM x2 + combine; block = bin (4 rows), 4 waves ----------
__global__ __launch_bounds__(256) void spmm_combine1(
    const int* __restrict__ bcnt, const uint2* __restrict__ bins,
    const uint2* __restrict__ ovf,
    const ushort16* __restrict__ supb, const float* __restrict__ s, const float* __restrict__ dk,
    const float* __restrict__ b1,
    const float* __restrict__ s2w, const float* __restrict__ d2w,
    const float* __restrict__ s2b, const float* __restrict__ d2b,
    float* __restrict__ emb, ushort16* __restrict__ embb,
    float* __restrict__ s_out, float* __restrict__ dk_out) {
    int b = blockIdx.x;
    int w = threadIdx.x >> 6, l = threadIdx.x & 63;
    const uint32* su = (const uint32*)supb;

    float a00=0,a01=0,a10=0,a11=0,a20=0,a21=0,a30=0,a31=0;
    float k00=0,k01=0,k10=0,k11=0,k20=0,k21=0,k30=0,k31=0;

#define PROC1(rec) { \
    uint32 rx = __builtin_amdgcn_readfirstlane((rec).x); \
    uint32 ry = __builtin_amdgcn_readfirstlane((rec).y); \
    float v = bflo(ry); \
    uint32 u = su[((size_t)(rx & 0xFFFFu) << 6) + l]; \
    float g0 = v * bflo(u), g1 = v * bfhi(u); \
    switch ((rx >> 16) & 7u) { \
      case 0: a00+=g0; a01+=g1; break; \
      case 1: a10+=g0; a11+=g1; break; \
      case 2: a20+=g0; a21+=g1; break; \
      case 3: a30+=g0; a31+=g1; break; \
      case 4: k00+=g0; k01+=g1; break; \
      case 5: k10+=g0; k11+=g1; break; \
      case 6: k20+=g0; k21+=g1; break; \
      default: k30+=g0; k31+=g1; break; \
    } }

    for (int sub = 0; sub < NSUB; ++sub) {
        int slot = b * NSUB + sub;
        const uint2* bp = bins + (size_t)slot * CAPS;
        int d = min(bcnt[slot], CAPS);
        int e = w;
        for (; e + 4 < d; e += 8) { uint2 rA = bp[e]; uint2 rB = bp[e + 4]; PROC1(rA); PROC1(rB); }
        for (; e < d; e += 4) { uint2 rA = bp[e]; PROC1(rA); }
    }
#undef PROC1

    __shared__ float red[4][16][64];
    red[w][0][l]=a00;  red[w][1][l]=a01;  red[w][2][l]=a10;  red[w][3][l]=a11;
    red[w][4][l]=a20;  red[w][5][l]=a21;  red[w][6][l]=a30;  red[w][7][l]=a31;
    red[w][8][l]=k00;  red[w][9][l]=k01;  red[w][10][l]=k10; red[w][11][l]=k11;
    red[w][12][l]=k20; red[w][13][l]=k21; red[w][14][l]=k30; red[w][15][l]=k31;
    __syncthreads();

    float accA0=0, accA1=0, accK0=0, accK1=0;
    #pragma unroll
    for (int wv = 0; wv < 4; ++wv) {
        accA0 += red[wv][w*2+0][l];
        accA1 += red[wv][w*2+1][l];
        accK0 += red[wv][8+w*2+0][l];
        accK1 += red[wv][8+w*2+1][l];
    }

    int r = b * 4 + w;
    int nov = min(bcnt[NBINS * NSUB], OVF_CAP);
    for (int i = 0; i < nov; ++i) {
        uint2 t = ovf[i];
        if ((int)(t.x & 0xFFFFu) != r) continue;
        float v = bfhi(t.y);
        uint32 u = su[((size_t)(t.y & 0xFFFFu) << 6) + l];
        if (t.x & 0x10000u) { accK0 += v * bflo(u); accK1 += v * bfhi(u); }
        else                { accA0 += v * bflo(u); accA1 += v * bfhi(u); }
    }

    float si = s[r];
    float g = GAMMA * dk[r];
    uint32 ui = su[((size_t)r << 6) + l];
    int c0i = l * 2, c1i = l * 2 + 1;
    float o0 = si * accA0 + (1.f - si) * accK0 + g * bflo(ui) + b1[c0i] * (1.f + g);
    float o1 = si * accA1 + (1.f - si) * accK1 + g * bfhi(ui) + b1[c1i] * (1.f + g);

    *reinterpret_cast<float2*>(emb + (size_t)r * 128 + c0i) = make_float2(o0, o1);
    ((uint32*)embb)[((size_t)r << 6) + l] = pack2bf(o0, o1);

    float as = o0 * s2w[c0i] + o1 * s2w[c1i];
    float ad = o0 * d2w[c0i] + o1 * d2w[c1i];
    #pragma unroll
    for (int off = 32; off; off >>= 1) {
        as += __shfl_xor(as, off);
        ad += __shfl_xor(ad, off);
    }
    if (l == 0) {
        s_out[r] = 1.f / (1.f + __expf(-(as + s2b[0])));
        dk_out[r] = ad + d2b[0];
    }
}

// ---------- layer-2 SPMM x2 + combine + log_softmax; block = bin (4 rows) ----------
__global__ __launch_bounds__(256) void spmm_combine2_lsm(
    const int* __restrict__ bcnt, const uint2* __restrict__ bins,
    const uint2* __restrict__ ovf,
    const ushort16* __restrict__ supb, const float* __restrict__ supf,
    const float* __restrict__ s, const float* __restrict__ dk,
    const float* __restrict__ b2, float* __restrict__ out) {
    int b = blockIdx.x;
    int w = threadIdx.x >> 6, l = threadIdx.x & 63;
    bool act = l < 20;
    const uint32* su = (const uint32*)supb;

    float a00=0,a01=0,a10=0,a11=0,a20=0,a21=0,a30=0,a31=0;
    float k00=0,k01=0,k10=0,k11=0,k20=0,k21=0,k30=0,k31=0;

#define PROC2(rec) { \
    uint32 rx = __builtin_amdgcn_readfirstlane((rec).x); \
    uint32 ry = __builtin_amdgcn_readfirstlane((rec).y); \
    float v = bflo(ry); \
    float g0 = 0.f, g1 = 0.f; \
    if (act) { \
        uint32 u = su[(size_t)(rx & 0xFFFFu) * 20 + l]; \
        g0 = v * bflo(u); g1 = v * bfhi(u); \
    } \
    switch ((rx >> 16) & 7u) { \
      case 0: a00+=g0; a01+=g1; break; \
      case 1: a10+=g0; a11+=g1; break; \
      case 2: a20+=g0; a21+=g1; break; \
      case 3: a30+=g0; a31+=g1; break; \
      case 4: k00+=g0; k01+=g1; break; \
      case 5: k10+=g0; k11+=g1; break; \
      case 6: k20+=g0; k21+=g1; break; \
      default: k30+=g0; k31+=g1; break; \
    } }

    for (int sub = 0; sub < NSUB; ++sub) {
        int slot = b * NSUB + sub;
        const uint2* bp = bins + (size_t)slot * CAPS;
        int d = min(bcnt[slot], CAPS);
        int e = w;
        for (; e + 4 < d; e += 8) { uint2 rA = bp[e]; uint2 rB = bp[e + 4]; PROC2(rA); PROC2(rB); }
        for (; e < d; e += 4) { uint2 rA = bp[e]; PROC2(rA); }
    }
#undef PROC2

    __shared__ float red[4][16][64];
    red[w][0][l]=a00;  red[w][1][l]=a01;  red[w][2][l]=a10;  red[w][3][l]=a11;
    red[w][4][l]=a20;  red[w][5][l]=a21;  red[w][6][l]=a30;  red[w][7][l]=a31;
    red[w][8][l]=k00;  red[w][9][l]=k01;  red[w][10][l]=k10; red[w][11][l]=k11;
    red[w][12][l]=k20; red[w][13][l]=k21; red[w][14][l]=k30; red[w][15][l]=k31;
    __syncthreads();

    float accA0=0, accA1=0, accK0=0, accK1=0;
    #pragma unroll
    for (int wv = 0; wv < 4; ++wv) {
        accA0 += red[wv][w*2+0][l];
        accA1 += red[wv][w*2+1][l];
        accK0 += red[wv][8+w*2+0][l];
        accK1 += red[wv][8+w*2+1][l];
    }

    int r = b * 4 + w;
    int nov = min(bcnt[NBINS * NSUB], OVF_CAP);
    for (int i = 0; i < nov; ++i) {
        uint2 t = ovf[i];
        if ((int)(t.x & 0xFFFFu) != r) continue;
        float v = bfhi(t.y);
        if (act) {
            uint32 u = su[(size_t)(t.y & 0xFFFFu) * 20 + l];
            if (t.x & 0x10000u) { accK0 += v * bflo(u); accK1 += v * bfhi(u); }
            else                { accA0 += v * bflo(u); accA1 += v * bfhi(u); }
        }
    }

    float si = s[r];
    float gg = GAMMA * dk[r];
    float z0 = -INFINITY, z1 = -INFINITY;
    if (act) {
        float2 iv = *reinterpret_cast<const float2*>(supf + (size_t)r * 40 + l * 2);
        z0 = si * accA0 + (1.f - si) * accK0 + gg * iv.x + b2[l * 2] * (1.f + gg);
        z1 = si * accA1 + (1.f - si) * accK1 + gg * iv.y + b2[l * 2 + 1] * (1.f + gg);
    }
    float m = fmaxf(z0, z1);
    #pragma unroll
    for (int off = 16; off; off >>= 1) m = fmaxf(m, __shfl_xor(m, off));
    float ex = act ? (__expf(z0 - m) + __expf(z1 - m)) : 0.f;
    #pragma unroll
    for (int off = 16; off; off >>= 1) ex += __shfl_xor(ex, off);
    float lse = m + __logf(ex);
    if (act)
        *reinterpret_cast<float2*>(out + (size_t)r * 40 + l * 2) = make_float2(z0 - lse, z1 - lse);
}

static inline size_t align256(size_t x) { return (x + 255) & ~(size_t)255; }

extern "C" void kernel_launch(void* const* d_in, const int* in_sizes, int n_in,
                              void* d_out, int out_size, void* d_ws, size_t ws_size,
                              hipStream_t stream) {
    const int N = 50000, C = 40;

    const float* fea     = (const float*)d_in[0];
    const int*   adj_row = (const int*)d_in[1];
    const int*   adj_col = (const int*)d_in[2];
    const float* adj_val = (const float*)d_in[3];
    const int*   knn_row = (const int*)d_in[4];
    const int*   knn_col = (const int*)d_in[5];
    const float* knn_val = (const float*)d_in[6];
    const float* W1      = (const float*)d_in[7];
    const float* b1      = (const float*)d_in[8];
    const float* W2      = (const float*)d_in[9];
    const float* b2      = (const float*)d_in[10];
    const float* score1  = (const float*)d_in[11];
    const float* score2  = (const float*)d_in[12];
    const float* sbias1  = (const float*)d_in[13];
    const float* sbias2  = (const float*)d_in[14];
    const float* Dk1     = (const float*)d_in[15];
    const float* Dk2     = (const float*)d_in[16];
    const float* Dbias1  = (const float*)d_in[17];
    const float* Dbias2  = (const float*)d_in[18];

    const int E  = in_sizes[1];
    const int EK = in_sizes[4];

    float* out_lsm = (float*)d_out;
    float* emb     = out_lsm + (size_t)N * C;

    // workspace carve (~52 MB). sup2/sup2b overlay sup1b (dead after spmm_combine1).
    char* wp = (char*)d_ws;
    ushort16* W1bt = (ushort16*)wp; wp += align256((size_t)128 * 512 * 2);
    ushort16* W2bt = (ushort16*)wp; wp += align256((size_t)48 * 128 * 2);
    char* sup1_region = wp;          wp += align256((size_t)N * 128 * 2);   // 12.8 MB
    ushort16* sup1b = (ushort16*)sup1_region;
    float* sup2     = (float*)sup1_region;                                   // 8 MB
    ushort16* sup2b = (ushort16*)(sup1_region + (size_t)N * 40 * 4);         // +4 MB
    ushort16* embb  = (ushort16*)wp; wp += align256((size_t)N * 128 * 2);
    float* s_buf  = (float*)wp; wp += align256((size_t)N * 4);
    float* dk_buf = (float*)wp; wp += align256((size_t)N * 4);
    int* bcnt = (int*)wp; wp += align256((size_t)(NBINS * NSUB + 1) * 4);
    uint2* bins = (uint2*)wp; wp += align256((size_t)NBINS * NSUB * CAPS * 8);  // 25.6 MB
    uint2* ovf  = (uint2*)wp; wp += align256((size_t)OVF_CAP * 8);

    int egrid = (max(E, EK) + 255) / 256;
    int mgrid = (N + 63) / 64;

    prep_wt<<<256, 256, 0, stream>>>(W1, W2, W1bt, W2bt, bcnt);

    gemm1_scatter<<<mgrid + egrid, 256, 0, stream>>>(
        fea, W1bt, score1, Dk1, sbias1, Dbias1, sup1b, s_buf, dk_buf, N, mgrid,
        adj_row, adj_col, adj_val, E, knn_row, knn_col, knn_val, EK,
        bcnt, bins, ovf);

    spmm_combine1<<<NBINS, 256, 0, stream>>>(bcnt, bins, ovf,
                                             sup1b, s_buf, dk_buf, b1,
                                             score2, Dk2, sbias2, Dbias2,
                                             emb, embb, s_buf, dk_buf);

    gemm2_mfma<<<mgrid, 256, 0, stream>>>(embb, W2bt, sup2, sup2b, N);

    spmm_combine2_lsm<<<NBINS, 256, 0, stream>>>(bcnt, bins, ovf,
                                                 sup2b, sup2, s_buf, dk_buf,
                                                 b2, out_lsm);

    (void)n_in; (void)out_size; (void)ws_size;
}

// Round 10
// 487.975 us; speedup vs baseline: 1.7939x; 1.7939x over previous
//
#include <hip/hip_runtime.h>
#include <hip/hip_bf16.h>
#include <cstdint>

#define GAMMA 0.1f
#define CAP 64
#define OVF_CAP 16384

typedef unsigned int  uint32;
typedef unsigned short ushort16;
typedef float f32x4 __attribute__((ext_vector_type(4)));
typedef __bf16 bf16x8 __attribute__((ext_vector_type(8)));

union U16x8 { uint4 u4; bf16x8 bv; };

static __device__ __forceinline__ ushort16 f2bf(float f) {
    union { float f; uint32 u; } x; x.f = f;
    uint32 r = (x.u + 0x7FFFu + ((x.u >> 16) & 1u)) >> 16;
    return (ushort16)r;
}
static __device__ __forceinline__ uint32 pack2bf(float lo, float hi) {
    return (uint32)f2bf(lo) | ((uint32)f2bf(hi) << 16);
}
static __device__ __forceinline__ float bflo(uint32 u) { return __uint_as_float(u << 16); }
static __device__ __forceinline__ float bfhi(uint32 u) { return __uint_as_float(u & 0xFFFF0000u); }

// ---------- prep: W1^T, W2^T bf16 + zero cursors ----------
__global__ __launch_bounds__(256) void prep_wt(const float* __restrict__ W1,
                                               const float* __restrict__ W2,
                                               ushort16* __restrict__ W1bt,
                                               ushort16* __restrict__ W2bt,
                                               int* __restrict__ cnt, int NC) {
    int t = blockIdx.x * 256 + threadIdx.x;
    if (t < 128 * 512) { int c = t >> 9, k = t & 511; W1bt[t] = f2bf(W1[k * 128 + c]); }
    if (t < 48 * 128)  { int c = t >> 7, k = t & 127; W2bt[t] = f2bf(c < 40 ? W2[k * 40 + c] : 0.f); }
    for (int j = t; j < NC; j += 256 * 256) cnt[j] = 0;
}

// ---------- fused: GEMM1 (blocks [0,mgrid)) + per-row scatter (rest) ----------
// record: col<<16 | bf16(val)  (4 B)
__global__ __launch_bounds__(256) void gemm1_scatter(
    const float* __restrict__ A, const ushort16* __restrict__ Bt,
    const float* __restrict__ s1w, const float* __restrict__ d1w,
    const float* __restrict__ s1b, const float* __restrict__ d1b,
    ushort16* __restrict__ Cb, float* __restrict__ s_out, float* __restrict__ dk_out,
    int M, int mgrid,
    const int* __restrict__ arow_, const int* __restrict__ acol_, const float* __restrict__ aval_, int E,
    const int* __restrict__ krow_, const int* __restrict__ kcol_, const float* __restrict__ kval_, int EK,
    int* __restrict__ cnt, int N,
    uint32* __restrict__ packed_a, uint32* __restrict__ packed_k,
    uint2* __restrict__ ovf_a, uint2* __restrict__ ovf_k) {
    int bid = blockIdx.x;
    if (bid >= mgrid) {
        int i = (bid - mgrid) * 256 + threadIdx.x;
        if (i < E) {
            int r = arow_[i];
            uint32 vb = (uint32)f2bf(aval_[i]);
            uint32 rec = ((uint32)acol_[i] << 16) | vb;
            int p = atomicAdd(&cnt[r], 1);
            if (p < CAP) __builtin_nontemporal_store(rec, &packed_a[(size_t)r * CAP + p]);
            else { int q = atomicAdd(&cnt[2 * N], 1); if (q < OVF_CAP) ovf_a[q] = make_uint2((uint32)r, (uint32)acol_[i] | (vb << 16)); }
        }
        if (i < EK) {
            int r = krow_[i];
            uint32 vb = (uint32)f2bf(kval_[i]);
            uint32 rec = ((uint32)kcol_[i] << 16) | vb;
            int p = atomicAdd(&cnt[N + r], 1);
            if (p < CAP) __builtin_nontemporal_store(rec, &packed_k[(size_t)r * CAP + p]);
            else { int q = atomicAdd(&cnt[2 * N + 1], 1); if (q < OVF_CAP) ovf_k[q] = make_uint2((uint32)r, (uint32)kcol_[i] | (vb << 16)); }
        }
        return;
    }
    // GEMM1 path
    int w = threadIdx.x >> 6, lane = threadIdx.x & 63;
    int row16 = lane & 15, kc = lane >> 4;
    int wrow0 = bid * 64 + w * 16;
    int r = wrow0 + row16;
    int rc = min(r, M - 1);
    const float* arow = A + (size_t)rc * 512;

    f32x4 acc[8];
    #pragma unroll
    for (int c = 0; c < 8; ++c) acc[c] = (f32x4){0.f, 0.f, 0.f, 0.f};
    float sdot = 0.f, ddot = 0.f;

    for (int ks = 0; ks < 16; ++ks) {
        int kb = ks * 32 + kc * 8;
        float4 a0 = *reinterpret_cast<const float4*>(arow + kb);
        float4 a1 = *reinterpret_cast<const float4*>(arow + kb + 4);
        float4 sw0 = *reinterpret_cast<const float4*>(s1w + kb);
        float4 sw1 = *reinterpret_cast<const float4*>(s1w + kb + 4);
        float4 dw0 = *reinterpret_cast<const float4*>(d1w + kb);
        float4 dw1 = *reinterpret_cast<const float4*>(d1w + kb + 4);
        sdot += a0.x * sw0.x + a0.y * sw0.y + a0.z * sw0.z + a0.w * sw0.w +
                a1.x * sw1.x + a1.y * sw1.y + a1.z * sw1.z + a1.w * sw1.w;
        ddot += a0.x * dw0.x + a0.y * dw0.y + a0.z * dw0.z + a0.w * dw0.w +
                a1.x * dw1.x + a1.y * dw1.y + a1.z * dw1.z + a1.w * dw1.w;
        U16x8 ua;
        ua.u4 = make_uint4(pack2bf(a0.x, a0.y), pack2bf(a0.z, a0.w),
                           pack2bf(a1.x, a1.y), pack2bf(a1.z, a1.w));
        #pragma unroll
        for (int c = 0; c < 8; ++c) {
            U16x8 ub;
            ub.u4 = *reinterpret_cast<const uint4*>(Bt + (size_t)(c * 16 + row16) * 512 + kb);
            acc[c] = __builtin_amdgcn_mfma_f32_16x16x32_bf16(ua.bv, ub.bv, acc[c], 0, 0, 0);
        }
    }

    sdot += __shfl_xor(sdot, 16); sdot += __shfl_xor(sdot, 32);
    ddot += __shfl_xor(ddot, 16); ddot += __shfl_xor(ddot, 32);
    if (kc == 0 && r < M) {
        s_out[r] = 1.f / (1.f + __expf(-(sdot + s1b[0])));
        dk_out[r] = ddot + d1b[0];
    }

    #pragma unroll
    for (int c = 0; c < 8; ++c) {
        #pragma unroll
        for (int i = 0; i < 4; ++i) {
            int orow = wrow0 + (lane >> 4) * 4 + i;
            if (orow < M) Cb[(size_t)orow * 128 + c * 16 + row16] = f2bf(acc[c][i]);
        }
    }
}

// ---------- GEMM2: sup2[M,40](f32)+sup2b(bf16) = embb[M,128](bf16) @ W2 ----------
__global__ __launch_bounds__(256) void gemm2_mfma(const ushort16* __restrict__ Ab,
                                                  const ushort16* __restrict__ Bt,
                                                  float* __restrict__ C,
                                                  ushort16* __restrict__ Cb,
                                                  int M) {
    int w = threadIdx.x >> 6, lane = threadIdx.x & 63;
    int row16 = lane & 15, kc = lane >> 4;
    int wrow0 = blockIdx.x * 64 + w * 16;
    int r = wrow0 + row16;
    int rc = min(r, M - 1);

    f32x4 acc[3];
    #pragma unroll
    for (int c = 0; c < 3; ++c) acc[c] = (f32x4){0.f, 0.f, 0.f, 0.f};

    #pragma unroll
    for (int ks = 0; ks < 4; ++ks) {
        int kb = ks * 32 + kc * 8;
        U16x8 ua;
        ua.u4 = *reinterpret_cast<const uint4*>(Ab + (size_t)rc * 128 + kb);
        #pragma unroll
        for (int c = 0; c < 3; ++c) {
            U16x8 ub;
            ub.u4 = *reinterpret_cast<const uint4*>(Bt + (size_t)(c * 16 + row16) * 128 + kb);
            acc[c] = __builtin_amdgcn_mfma_f32_16x16x32_bf16(ua.bv, ub.bv, acc[c], 0, 0, 0);
        }
    }

    #pragma unroll
    for (int c = 0; c < 3; ++c) {
        int col = c * 16 + row16;
        #pragma unroll
        for (int i = 0; i < 4; ++i) {
            int orow = wrow0 + (lane >> 4) * 4 + i;
            if (orow < M && col < 40) {
                C[(size_t)orow * 40 + col] = acc[c][i];
                Cb[(size_t)orow * 40 + col] = f2bf(acc[c][i]);
            }
        }
    }
}

// ---------- layer-1: per-row SPMM x2 (chunk-8 pipelined) + combine + layer-2 gates ----------
__global__ __launch_bounds__(256) void spmm_combine1(
    const int* __restrict__ cnt,
    const uint32* __restrict__ packed_a, const uint32* __restrict__ packed_k,
    const uint2* __restrict__ ovf_a, const uint2* __restrict__ ovf_k,
    const ushort16* __restrict__ supb, const float* __restrict__ s, const float* __restrict__ dk,
    const float* __restrict__ b1,
    const float* __restrict__ s2w, const float* __restrict__ d2w,
    const float* __restrict__ s2b, const float* __restrict__ d2b,
    float* __restrict__ emb, ushort16* __restrict__ embb,
    float* __restrict__ s_out, float* __restrict__ dk_out, int N) {
    int w = threadIdx.x >> 6, l = threadIdx.x & 63;
    int r = blockIdx.x * 4 + w;
    if (r >= N) return;
    const uint32* su = (const uint32*)supb;

    float a0 = 0.f, a1 = 0.f, k0 = 0.f, k1 = 0.f;
    {
        const uint32* pa = packed_a + (size_t)r * CAP;
        int d = min(cnt[r], CAP);
        for (int e = 0; e < d; e += 8) {
            uint32 rec[8], uu[8];
            #pragma unroll
            for (int j = 0; j < 8; ++j) rec[j] = pa[min(e + j, d - 1)];
            #pragma unroll
            for (int j = 0; j < 8; ++j) uu[j] = su[((size_t)(rec[j] >> 16) << 6) + l];
            #pragma unroll
            for (int j = 0; j < 8; ++j) {
                float v = (e + j < d) ? bflo(rec[j]) : 0.f;
                a0 += v * bflo(uu[j]); a1 += v * bfhi(uu[j]);
            }
        }
    }
    {
        const uint32* pk = packed_k + (size_t)r * CAP;
        int d = min(cnt[N + r], CAP);
        for (int e = 0; e < d; e += 8) {
            uint32 rec[8], uu[8];
            #pragma unroll
            for (int j = 0; j < 8; ++j) rec[j] = pk[min(e + j, d - 1)];
            #pragma unroll
            for (int j = 0; j < 8; ++j) uu[j] = su[((size_t)(rec[j] >> 16) << 6) + l];
            #pragma unroll
            for (int j = 0; j < 8; ++j) {
                float v = (e + j < d) ? bflo(rec[j]) : 0.f;
                k0 += v * bflo(uu[j]); k1 += v * bfhi(uu[j]);
            }
        }
    }
    // overflow (normally empty)
    int nova = min(cnt[2 * N], OVF_CAP);
    for (int i = 0; i < nova; ++i) {
        uint2 t = ovf_a[i];
        if ((int)t.x != r) continue;
        float v = bfhi(t.y);
        uint32 u = su[((size_t)(t.y & 0xFFFFu) << 6) + l];
        a0 += v * bflo(u); a1 += v * bfhi(u);
    }
    int novk = min(cnt[2 * N + 1], OVF_CAP);
    for (int i = 0; i < novk; ++i) {
        uint2 t = ovf_k[i];
        if ((int)t.x != r) continue;
        float v = bfhi(t.y);
        uint32 u = su[((size_t)(t.y & 0xFFFFu) << 6) + l];
        k0 += v * bflo(u); k1 += v * bfhi(u);
    }

    float si = s[r];
    float g = GAMMA * dk[r];
    uint32 ui = su[((size_t)r << 6) + l];
    int c0i = l * 2, c1i = l * 2 + 1;
    float o0 = si * a0 + (1.f - si) * k0 + g * bflo(ui) + b1[c0i] * (1.f + g);
    float o1 = si * a1 + (1.f - si) * k1 + g * bfhi(ui) + b1[c1i] * (1.f + g);

    *reinterpret_cast<float2*>(emb + (size_t)r * 128 + c0i) = make_float2(o0, o1);
    ((uint32*)embb)[((size_t)r << 6) + l] = pack2bf(o0, o1);

    float as = o0 * s2w[c0i] + o1 * s2w[c1i];
    float ad = o0 * d2w[c0i] + o1 * d2w[c1i];
    #pragma unroll
    for (int off = 32; off; off >>= 1) {
        as += __shfl_xor(as, off);
        ad += __shfl_xor(ad, off);
    }
    if (l == 0) {
        s_out[r] = 1.f / (1.f + __expf(-(as + s2b[0])));
        dk_out[r] = ad + d2b[0];
    }
}

// ---------- layer-2: per-row SPMM x2 (3 records/gather) + combine + log_softmax ----------
__global__ __launch_bounds__(256) void spmm_combine2_lsm(
    const int* __restrict__ cnt,
    const uint32* __restrict__ packed_a, const uint32* __restrict__ packed_k,
    const uint2* __restrict__ ovf_a, const uint2* __restrict__ ovf_k,
    const ushort16* __restrict__ supb, const float* __restrict__ supf,
    const float* __restrict__ s, const float* __restrict__ dk,
    const float* __restrict__ b2, float* __restrict__ out, int N) {
    int w = threadIdx.x >> 6, l = threadIdx.x & 63;
    int r = blockIdx.x * 4 + w;
    if (r >= N) return;
    int g = (l >= 40) ? 2 : ((l >= 20) ? 1 : 0);
    int li = l - g * 20;
    bool act = l < 60;
    const uint32* su = (const uint32*)supb;   // stride 20 words per row

    float a0 = 0.f, a1 = 0.f, k0 = 0.f, k1 = 0.f;
    {
        const uint32* pa = packed_a + (size_t)r * CAP;
        int d = min(cnt[r], CAP);
        for (int e = 0; e < d; e += 6) {
            uint32 rr[6];
            #pragma unroll
            for (int j = 0; j < 6; ++j) rr[j] = pa[min(e + j, d - 1)];
            uint32 rca = (g == 0) ? rr[0] : ((g == 1) ? rr[1] : rr[2]);
            uint32 rcb = (g == 0) ? rr[3] : ((g == 1) ? rr[4] : rr[5]);
            uint32 ua = su[(size_t)(rca >> 16) * 20 + li];
            uint32 ub = su[(size_t)(rcb >> 16) * 20 + li];
            float va = (act && (e + g) < d) ? bflo(rca) : 0.f;
            float vb = (act && (e + 3 + g) < d) ? bflo(rcb) : 0.f;
            a0 += va * bflo(ua) + vb * bflo(ub);
            a1 += va * bfhi(ua) + vb * bfhi(ub);
        }
    }
    {
        const uint32* pk = packed_k + (size_t)r * CAP;
        int d = min(cnt[N + r], CAP);
        for (int e = 0; e < d; e += 6) {
            uint32 rr[6];
            #pragma unroll
            for (int j = 0; j < 6; ++j) rr[j] = pk[min(e + j, d - 1)];
            uint32 rca = (g == 0) ? rr[0] : ((g == 1) ? rr[1] : rr[2]);
            uint32 rcb = (g == 0) ? rr[3] : ((g == 1) ? rr[4] : rr[5]);
            uint32 ua = su[(size_t)(rca >> 16) * 20 + li];
            uint32 ub = su[(size_t)(rcb >> 16) * 20 + li];
            float va = (act && (e + g) < d) ? bflo(rca) : 0.f;
            float vb = (act && (e + 3 + g) < d) ? bflo(rcb) : 0.f;
            k0 += va * bflo(ua) + vb * bflo(ub);
            k1 += va * bfhi(ua) + vb * bfhi(ub);
        }
    }
    // fold the 3 groups onto lanes 0..19
    {
        float t1, t2;
        t1 = __shfl(a0, (l + 20) & 63); t2 = __shfl(a0, (l + 40) & 63); a0 += t1 + t2;
        t1 = __shfl(a1, (l + 20) & 63); t2 = __shfl(a1, (l + 40) & 63); a1 += t1 + t2;
        t1 = __shfl(k0, (l + 20) & 63); t2 = __shfl(k0, (l + 40) & 63); k0 += t1 + t2;
        t1 = __shfl(k1, (l + 20) & 63); t2 = __shfl(k1, (l + 40) & 63); k1 += t1 + t2;
    }
    // overflow (normally empty) on lanes 0..19
    int nova = min(cnt[2 * N], OVF_CAP);
    for (int i = 0; i < nova; ++i) {
        uint2 t = ovf_a[i];
        if ((int)t.x != r) continue;
        if (l < 20) {
            float v = bfhi(t.y);
            uint32 u = su[(size_t)(t.y & 0xFFFFu) * 20 + l];
            a0 += v * bflo(u); a1 += v * bfhi(u);
        }
    }
    int novk = min(cnt[2 * N + 1], OVF_CAP);
    for (int i = 0; i < novk; ++i) {
        uint2 t = ovf_k[i];
        if ((int)t.x != r) continue;
        if (l < 20) {
            float v = bfhi(t.y);
            uint32 u = su[(size_t)(t.y & 0xFFFFu) * 20 + l];
            k0 += v * bflo(u); k1 += v * bfhi(u);
        }
    }

    float si = s[r];
    float gg = GAMMA * dk[r];
    float z0 = -INFINITY, z1 = -INFINITY;
    if (l < 20) {
        float2 iv = *reinterpret_cast<const float2*>(supf + (size_t)r * 40 + l * 2);
        z0 = si * a0 + (1.f - si) * k0 + gg * iv.x + b2[l * 2] * (1.f + gg);
        z1 = si * a1 + (1.f - si) * k1 + gg * iv.y + b2[l * 2 + 1] * (1.f + gg);
    }
    float m = fmaxf(z0, z1);
    #pragma unroll
    for (int off = 16; off; off >>= 1) m = fmaxf(m, __shfl_xor(m, off));
    float ex = (l < 20) ? (__expf(z0 - m) + __expf(z1 - m)) : 0.f;
    #pragma unroll
    for (int off = 16; off; off >>= 1) ex += __shfl_xor(ex, off);
    float lse = m + __logf(ex);
    if (l < 20)
        *reinterpret_cast<float2*>(out + (size_t)r * 40 + l * 2) = make_float2(z0 - lse, z1 - lse);
}

static inline size_t align256(size_t x) { return (x + 255) & ~(size_t)255; }

extern "C" void kernel_launch(void* const* d_in, const int* in_sizes, int n_in,
                              void* d_out, int out_size, void* d_ws, size_t ws_size,
                              hipStream_t stream) {
    const int N = 50000, C = 40;

    const float* fea     = (const float*)d_in[0];
    const int*   adj_row = (const int*)d_in[1];
    const int*   adj_col = (const int*)d_in[2];
    const float* adj_val = (const float*)d_in[3];
    const int*   knn_row = (const int*)d_in[4];
    const int*   knn_col = (const int*)d_in[5];
    const float* knn_val = (const float*)d_in[6];
    const float* W1      = (const float*)d_in[7];
    const float* b1      = (const float*)d_in[8];
    const float* W2      = (const float*)d_in[9];
    const float* b2      = (const float*)d_in[10];
    const float* score1  = (const float*)d_in[11];
    const float* score2  = (const float*)d_in[12];
    const float* sbias1  = (const float*)d_in[13];
    const float* sbias2  = (const float*)d_in[14];
    const float* Dk1     = (const float*)d_in[15];
    const float* Dk2     = (const float*)d_in[16];
    const float* Dbias1  = (const float*)d_in[17];
    const float* Dbias2  = (const float*)d_in[18];

    const int E  = in_sizes[1];
    const int EK = in_sizes[4];

    float* out_lsm = (float*)d_out;
    float* emb     = out_lsm + (size_t)N * C;

    // workspace carve. sup2/sup2b overlay sup1b (dead after spmm_combine1).
    char* wp = (char*)d_ws;
    ushort16* W1bt = (ushort16*)wp; wp += align256((size_t)128 * 512 * 2);
    ushort16* W2bt = (ushort16*)wp; wp += align256((size_t)48 * 128 * 2);
    char* sup1_region = wp;          wp += align256((size_t)N * 128 * 2);   // 12.8 MB
    ushort16* sup1b = (ushort16*)sup1_region;
    float* sup2     = (float*)sup1_region;                                   // 8 MB
    ushort16* sup2b = (ushort16*)(sup1_region + (size_t)N * 40 * 4);         // +4 MB
    ushort16* embb  = (ushort16*)wp; wp += align256((size_t)N * 128 * 2);
    float* s_buf  = (float*)wp; wp += align256((size_t)N * 4);
    float* dk_buf = (float*)wp; wp += align256((size_t)N * 4);
    int* cnt  = (int*)wp; wp += align256((size_t)(2 * N + 2) * 4);
    uint32* packed_a = (uint32*)wp; wp += align256((size_t)N * CAP * 4);     // 12.8 MB
    uint32* packed_k = (uint32*)wp; wp += align256((size_t)N * CAP * 4);     // 12.8 MB
    uint2* ovf_a = (uint2*)wp; wp += align256((size_t)OVF_CAP * 8);
    uint2* ovf_k = (uint2*)wp; wp += align256((size_t)OVF_CAP * 8);

    int egrid = (max(E, EK) + 255) / 256;
    int mgrid = (N + 63) / 64;

    prep_wt<<<256, 256, 0, stream>>>(W1, W2, W1bt, W2bt, cnt, 2 * N + 2);

    gemm1_scatter<<<mgrid + egrid, 256, 0, stream>>>(
        fea, W1bt, score1, Dk1, sbias1, Dbias1, sup1b, s_buf, dk_buf, N, mgrid,
        adj_row, adj_col, adj_val, E, knn_row, knn_col, knn_val, EK,
        cnt, N, packed_a, packed_k, ovf_a, ovf_k);

    spmm_combine1<<<(N + 3) / 4, 256, 0, stream>>>(cnt, packed_a, packed_k, ovf_a, ovf_k,
                                                   sup1b, s_buf, dk_buf, b1,
                                                   score2, Dk2, sbias2, Dbias2,
                                                   emb, embb, s_buf, dk_buf, N);

    gemm2_mfma<<<mgrid, 256, 0, stream>>>(embb, W2bt, sup2, sup2b, N);

    spmm_combine2_lsm<<<(N + 3) / 4, 256, 0, stream>>>(cnt, packed_a, packed_k, ovf_a, ovf_k,
                                                       sup2b, sup2, s_buf, dk_buf,
                                                       b2, out_lsm, N);

    (void)n_in; (void)out_size; (void)ws_size;
}